// Round 18
// baseline (187.472 us; speedup 1.0000x reference)
//
#include <hip/hip_runtime.h>
#include <hip/hip_bf16.h>

#define NBATCH 32
#define NG 1024
#define DM 256

typedef short bf16x8 __attribute__((ext_vector_type(8)));
typedef float f32x4 __attribute__((ext_vector_type(4)));
typedef unsigned short u16x4 __attribute__((ext_vector_type(4)));
typedef unsigned short u16x8 __attribute__((ext_vector_type(8)));

static __device__ __forceinline__ unsigned short f2bf(float f) {
    __hip_bfloat16 h = __float2bfloat16(f);
    return *reinterpret_cast<unsigned short*>(&h);
}
static __device__ __forceinline__ float bf2f(unsigned short u) {
    unsigned int x = ((unsigned int)u) << 16;
    return *reinterpret_cast<float*>(&x);
}

// async global->LDS, 16B per lane. LDS dest wave-uniform (HW adds lane*16);
// global source is per-lane.
static __device__ __forceinline__ void gload16(const void* g, void* l) {
    __builtin_amdgcn_global_load_lds(
        (const __attribute__((address_space(1))) unsigned int*)g,
        (__attribute__((address_space(3))) unsigned int*)l, 16, 0, 0);
}

// counted-vmcnt barrier pairs (T4)
static __device__ __forceinline__ void wait_vm8_bar() {
    asm volatile("s_waitcnt vmcnt(8)" ::: "memory");
    asm volatile("s_barrier" ::: "memory");
    __builtin_amdgcn_sched_barrier(0);
}
static __device__ __forceinline__ void wait_vm4_bar() {
    asm volatile("s_waitcnt vmcnt(4)" ::: "memory");
    asm volatile("s_barrier" ::: "memory");
    __builtin_amdgcn_sched_barrier(0);
}
static __device__ __forceinline__ void wait_vm0_bar() {
    asm volatile("s_waitcnt vmcnt(0)" ::: "memory");
    asm volatile("s_barrier" ::: "memory");
    __builtin_amdgcn_sched_barrier(0);
}
static __device__ __forceinline__ void bar_only() {
    asm volatile("s_barrier" ::: "memory");
}

// ---------------------------------------------------------------------------
// Kernel W: pack Wq|Wk|Wv (f32 [e][d]) -> bf16 Wb[3][256][256]. L2-resident.
// ---------------------------------------------------------------------------
__global__ __launch_bounds__(256) void wpack_kernel(
    const float* __restrict__ Wq, const float* __restrict__ Wk,
    const float* __restrict__ Wv, unsigned short* __restrict__ Wb)
{
    const int i4 = (blockIdx.x * 256 + threadIdx.x) * 4;   // grid 192
    const int t = i4 >> 16;
    const int off = i4 & 65535;
    const float* src = (t == 0) ? Wq : (t == 1) ? Wk : Wv;
    float4 v = *(const float4*)(src + off);
    *(u16x4*)(Wb + i4) = (u16x4){ f2bf(v.x), f2bf(v.y), f2bf(v.z), f2bf(v.w) };
}

// ---------------------------------------------------------------------------
// Kernel X: q|k|v f32 -> bf16 stream convert, one launch. grid 12288.
// ---------------------------------------------------------------------------
__global__ __launch_bounds__(256) void conv3_kernel(
    const float* __restrict__ q, const float* __restrict__ k,
    const float* __restrict__ v, unsigned short* __restrict__ Xb)
{
    const int sel = blockIdx.x >> 12;
    const float* src = (sel == 0) ? q : (sel == 1) ? k : v;
    const size_t i8 = (((size_t)(blockIdx.x & 4095)) * 256 + threadIdx.x) * 8;
    float4 a = *(const float4*)(src + i8);
    float4 b = *(const float4*)(src + i8 + 4);
    *(u16x8*)(Xb + (size_t)sel * NBATCH * NG * DM + i8) =
        (u16x8){ f2bf(a.x), f2bf(a.y), f2bf(a.z), f2bf(a.w),
                 f2bf(b.x), f2bf(b.y), f2bf(b.z), f2bf(b.w) };
}

// ---------------------------------------------------------------------------
// Kernel B: exp_A = bf16(exp2(sc * dist)), full batch. grid 16384.
// ---------------------------------------------------------------------------
__global__ __launch_bounds__(256) void exp_kernel(
    const float* __restrict__ dist, unsigned short* __restrict__ ea,
    const float* __restrict__ alpha_raw)
{
    const float alpha = log1pf(__expf(alpha_raw[0])) + 1e-6f;
    const float sc = -alpha * 10.0f * 1.44269504088896f;
    const size_t i8 = ((size_t)blockIdx.x * 256 + threadIdx.x) * 8;
    float4 v0 = *(const float4*)(dist + i8);
    float4 v1 = *(const float4*)(dist + i8 + 4);
    u16x8 o = { f2bf(exp2f(sc * v0.x)), f2bf(exp2f(sc * v0.y)),
                f2bf(exp2f(sc * v0.z)), f2bf(exp2f(sc * v0.w)),
                f2bf(exp2f(sc * v1.x)), f2bf(exp2f(sc * v1.y)),
                f2bf(exp2f(sc * v1.z)), f2bf(exp2f(sc * v1.w)) };
    *(u16x8*)(ea + i8) = o;
}

// ---------------------------------------------------------------------------
// Kernel Q: qb = bf16(Xq @ Wq^T + bq)  (pre-sigmoid; attn applies sigmoid).
// dbuf + counted-vmcnt (T4), proven structure.
// ---------------------------------------------------------------------------
__global__ __launch_bounds__(256) void projq_kernel(
    const unsigned short* __restrict__ Xq,   // [32768][256] bf16
    const unsigned short* __restrict__ Wb,   // [256][256] bf16 (Wq)
    const float* __restrict__ bq,
    unsigned short* __restrict__ qb)         // [32768][256] bf16
{
    __shared__ __align__(128) unsigned short lds[2][2][128 * 64];

    const int bid = blockIdx.x;
    const int mt = bid >> 1, nt = bid & 1;
    const int tid = threadIdx.x;
    const int w = tid >> 6, lane = tid & 63;
    const int wm = w >> 1, wn = w & 1;
    const int l15 = lane & 15, lhi = lane >> 4;
    const int lr = lane >> 3, sl = lane & 7;
    const int sp = sl ^ lr;

    const char* Abase = (const char*)(Xq + (size_t)mt * 128 * 256);
    const char* Wbase = (const char*)(Wb + (size_t)nt * 128 * 256);

    f32x4 acc[4][4];
    #pragma unroll
    for (int mi = 0; mi < 4; ++mi)
        #pragma unroll
        for (int ni = 0; ni < 4; ++ni)
            acc[mi][ni] = (f32x4){0.f, 0.f, 0.f, 0.f};

    auto STAGE = [&](int buf, int t) {
        #pragma unroll
        for (int i = 0; i < 4; ++i) {
            const int r = w * 32 + i * 8 + lr;
            gload16(Abase + (size_t)r * 512 + t * 128 + sp * 16,
                    (char*)&lds[buf][0][0] + w * 4096 + i * 1024);
            gload16(Wbase + (size_t)r * 512 + t * 128 + sp * 16,
                    (char*)&lds[buf][1][0] + w * 4096 + i * 1024);
        }
    };

    STAGE(0, 0);
    int cur = 0;
    for (int t = 0; t < 4; ++t) {
        if (t < 3) { STAGE(cur ^ 1, t + 1); wait_vm8_bar(); }
        else       { wait_vm0_bar(); }
        const char* Ab = (const char*)&lds[cur][0][0];
        const char* Bb = (const char*)&lds[cur][1][0];
        #pragma unroll
        for (int kk = 0; kk < 2; ++kk) {
            bf16x8 af[4], bfr[4];
            #pragma unroll
            for (int mi = 0; mi < 4; ++mi) {
                const int tr = wm * 64 + mi * 16 + l15;
                af[mi] = *(const bf16x8*)(Ab + ((tr * 128 + kk * 64 + lhi * 16) ^ ((tr & 7) << 4)));
            }
            #pragma unroll
            for (int ni = 0; ni < 4; ++ni) {
                const int tr = wn * 64 + ni * 16 + l15;
                bfr[ni] = *(const bf16x8*)(Bb + ((tr * 128 + kk * 64 + lhi * 16) ^ ((tr & 7) << 4)));
            }
            #pragma unroll
            for (int mi = 0; mi < 4; ++mi)
                #pragma unroll
                for (int ni = 0; ni < 4; ++ni)
                    acc[mi][ni] = __builtin_amdgcn_mfma_f32_16x16x32_bf16(
                        af[mi], bfr[ni], acc[mi][ni], 0, 0, 0);
        }
        bar_only();
        cur ^= 1;
    }

    #pragma unroll
    for (int ni = 0; ni < 4; ++ni) {
        const int c = nt * 128 + wn * 64 + ni * 16 + l15;
        const float bqs = bq[c];
        #pragma unroll
        for (int mi = 0; mi < 4; ++mi)
            #pragma unroll
            for (int r = 0; r < 4; ++r) {
                const size_t R = (size_t)mt * 128 + wm * 64 + mi * 16 + lhi * 4 + r;
                qb[R * DM + c] = f2bf(acc[mi][ni][r] + bqs);
            }
    }
}

// ---------------------------------------------------------------------------
// Kernel KV: k, v projections fused (row = [k 64B | v 64B]); dbuf + T4.
// Pt rows 2c/2c+1 = exp(k)*v / exp(k).
// ---------------------------------------------------------------------------
__global__ __launch_bounds__(256) void projkv_kernel(
    const unsigned short* __restrict__ Xk,
    const unsigned short* __restrict__ Xv,
    const unsigned short* __restrict__ Wkb,
    const unsigned short* __restrict__ Wvb,
    const float* __restrict__ bk, const float* __restrict__ bv,
    unsigned short* __restrict__ Pt)
{
    __shared__ __align__(128) unsigned short lds[2][2][128 * 64];

    const int bid = blockIdx.x;
    const int mt = bid >> 1, nt = bid & 1;
    const int tid = threadIdx.x;
    const int w = tid >> 6, lane = tid & 63;
    const int wm = w >> 1, wn = w & 1;
    const int l15 = lane & 15, lhi = lane >> 4;
    const int lr = lane >> 3, sl = lane & 7;
    const int sp = sl ^ lr;
    const int g16 = (sp & 3) * 16;

    f32x4 kacc[4][4], vacc[4][4];
    #pragma unroll
    for (int mi = 0; mi < 4; ++mi)
        #pragma unroll
        for (int ni = 0; ni < 4; ++ni) {
            kacc[mi][ni] = (f32x4){0.f, 0.f, 0.f, 0.f};
            vacc[mi][ni] = (f32x4){0.f, 0.f, 0.f, 0.f};
        }

    auto STAGE = [&](int buf, int t) {
        #pragma unroll
        for (int i = 0; i < 4; ++i) {
            const int r = w * 32 + i * 8 + lr;
            const char* asrc = (sp < 4 ? (const char*)Xk : (const char*)Xv)
                               + (size_t)(mt * 128 + r) * 512 + t * 64 + g16;
            gload16(asrc, (char*)&lds[buf][0][0] + w * 4096 + i * 1024);
            const char* wsrc = (sp < 4 ? (const char*)Wkb : (const char*)Wvb)
                               + (size_t)(nt * 128 + r) * 512 + t * 64 + g16;
            gload16(wsrc, (char*)&lds[buf][1][0] + w * 4096 + i * 1024);
        }
    };

    STAGE(0, 0);
    int cur = 0;
    for (int t = 0; t < 8; ++t) {
        if (t < 7) { STAGE(cur ^ 1, t + 1); wait_vm8_bar(); }
        else       { wait_vm0_bar(); }
        const char* Ab = (const char*)&lds[cur][0][0];
        const char* Bb = (const char*)&lds[cur][1][0];
        bf16x8 kaf[4], vaf[4], kbf[4], vbf[4];
        #pragma unroll
        for (int mi = 0; mi < 4; ++mi) {
            const int tr = wm * 64 + mi * 16 + l15;
            const int sw = (tr & 7) << 4;
            kaf[mi] = *(const bf16x8*)(Ab + ((tr * 128 + lhi * 16) ^ sw));
            vaf[mi] = *(const bf16x8*)(Ab + ((tr * 128 + 64 + lhi * 16) ^ sw));
        }
        #pragma unroll
        for (int ni = 0; ni < 4; ++ni) {
            const int tr = wn * 64 + ni * 16 + l15;
            const int sw = (tr & 7) << 4;
            kbf[ni] = *(const bf16x8*)(Bb + ((tr * 128 + lhi * 16) ^ sw));
            vbf[ni] = *(const bf16x8*)(Bb + ((tr * 128 + 64 + lhi * 16) ^ sw));
        }
        #pragma unroll
        for (int mi = 0; mi < 4; ++mi)
            #pragma unroll
            for (int ni = 0; ni < 4; ++ni) {
                kacc[mi][ni] = __builtin_amdgcn_mfma_f32_16x16x32_bf16(
                    kaf[mi], kbf[ni], kacc[mi][ni], 0, 0, 0);
                vacc[mi][ni] = __builtin_amdgcn_mfma_f32_16x16x32_bf16(
                    vaf[mi], vbf[ni], vacc[mi][ni], 0, 0, 0);
            }
        bar_only();
        cur ^= 1;
    }

    const int b = (mt * 128) >> 10;
    const int kb0 = (mt * 128) & 1023;
    #pragma unroll
    for (int ni = 0; ni < 4; ++ni) {
        const int c = nt * 128 + wn * 64 + ni * 16 + l15;
        const float bks = bk[c], bvs = bv[c];
        #pragma unroll
        for (int mi = 0; mi < 4; ++mi) {
            unsigned short p1[4], p2[4];
            #pragma unroll
            for (int r = 0; r < 4; ++r) {
                const float ek = __expf(kacc[mi][ni][r] + bks);
                const float vv = vacc[mi][ni][r] + bvs;
                p1[r] = f2bf(ek * vv);
                p2[r] = f2bf(ek);
            }
            const int kidx = kb0 + wm * 64 + mi * 16 + lhi * 4;
            *(u16x4*)&Pt[((size_t)b * 512 + 2 * c    ) * NG + kidx] =
                (u16x4){p1[0], p1[1], p1[2], p1[3]};
            *(u16x4*)&Pt[((size_t)b * 512 + 2 * c + 1) * NG + kidx] =
                (u16x4){p2[0], p2[1], p2[2], p2[3]};
        }
    }
}

// ---------------------------------------------------------------------------
// Kernel C: out = sigmoid(q) * (num/den). 128x128 tile, BK=32, 256 threads
// (4 waves 2x2), dbuf 32 KB LDS -> 4 BLOCKS/CU (launch_bounds(256,4)).
// Staging throughput scales with resident blocks (1/CU->3.3, 2->7.4,
// 4->~12 TB/s effective) — proven r17 (attn ~40 us).
// Counted vmcnt(4); r12's proven 64B-row XOR swizzle (0 conflicts).
// grid 1024 = 32b x 8m x 4n, XCD-chunked.
// ---------------------------------------------------------------------------
__global__ __launch_bounds__(256, 4) void attn_kernel(
    const unsigned short* __restrict__ ea,
    const unsigned short* __restrict__ Pt,
    const unsigned short* __restrict__ qb,
    float* __restrict__ out)
{
    __shared__ __align__(128) char lds[2][2][8192];   // [buf][A/B][128 rows x 64B]

    const int bid = blockIdx.x;
    const int l = (bid & 7) * 128 + (bid >> 3);   // bijective (1024 % 8 == 0)
    const int b = l >> 5;
    const int m = (l >> 2) & 7;
    const int n = l & 3;

    const int tid = threadIdx.x;
    const int w = tid >> 6, lane = tid & 63;
    const int wm = w >> 1, wn = w & 1;
    const int l15 = lane & 15, lhi = lane >> 4;
    const int xv = (l15 >> 1) & 3;               // read-side swizzle XOR

    const int sr = tid >> 2;                     // staging row 0..63 (+64 rnd 2)
    const int sgl = tid & 3;                     // logical granule

    const char* Abase = (const char*)(ea + ((size_t)b * NG + m * 128) * NG);
    const char* Bbase = (const char*)(Pt + ((size_t)b * 512 + n * 128) * NG);

    f32x4 acc[4][4];
    #pragma unroll
    for (int mi = 0; mi < 4; ++mi)
        #pragma unroll
        for (int ni = 0; ni < 4; ++ni)
            acc[mi][ni] = (f32x4){0.f, 0.f, 0.f, 0.f};

    // stage K-step t (32 bf16 = 64B per row, 128 rows each op): 4 gload/thread
    auto STAGE = [&](int buf, int t) {
        #pragma unroll
        for (int j = 0; j < 2; ++j) {
            const int r = j * 64 + sr;
            const int sg = sgl ^ ((r >> 1) & 3);
            gload16(Abase + (size_t)r * 2048 + t * 64 + sg * 16,
                    &lds[buf][0][0] + j * 4096 + w * 1024);
            gload16(Bbase + (size_t)r * 2048 + t * 64 + sg * 16,
                    &lds[buf][1][0] + j * 4096 + w * 1024);
        }
    };

    STAGE(0, 0);
    int cur = 0;
    for (int t = 0; t < 32; ++t) {
        if (t < 31) { STAGE(cur ^ 1, t + 1); wait_vm4_bar(); }
        else        { wait_vm0_bar(); }
        const char* Ab = &lds[cur][0][0];
        const char* Bb = &lds[cur][1][0];
        __builtin_amdgcn_s_setprio(1);
        bf16x8 af[4], bfr[4];
        #pragma unroll
        for (int mi = 0; mi < 4; ++mi) {
            const int tr = wm * 64 + mi * 16 + l15;
            af[mi] = *(const bf16x8*)(Ab + tr * 64 + ((lhi ^ xv) * 16));
        }
        #pragma unroll
        for (int ni = 0; ni < 4; ++ni) {
            const int tr = wn * 64 + ni * 16 + l15;
            bfr[ni] = *(const bf16x8*)(Bb + tr * 64 + ((lhi ^ xv) * 16));
        }
        #pragma unroll
        for (int mi = 0; mi < 4; ++mi)
            #pragma unroll
            for (int ni = 0; ni < 4; ++ni)
                acc[mi][ni] = __builtin_amdgcn_mfma_f32_16x16x32_bf16(
                    af[mi], bfr[ni], acc[mi][ni], 0, 0, 0);
        __builtin_amdgcn_s_setprio(0);
        bar_only();
        cur ^= 1;
    }

    // epilogue: even col = numerator, odd = denominator (same d); sigmoid(q)
    const int parity = lane & 1;
    #pragma unroll
    for (int mi = 0; mi < 4; ++mi)
        #pragma unroll
        for (int ni = 0; ni < 4; ++ni)
            #pragma unroll
            for (int r = 0; r < 4; ++r) {
                const float own = acc[mi][ni][r];
                const float other = __shfl_xor(own, 1, 64);
                if (!parity) {
                    const int colg = n * 128 + wn * 64 + ni * 16 + l15;   // even
                    const int d = colg >> 1;
                    const int rowg = m * 128 + wm * 64 + mi * 16 + lhi * 4 + r;
                    const size_t idx = ((size_t)b * NG + rowg) * DM + d;
                    const float qv = bf2f(qb[idx]);
                    const float sig = 1.0f / (1.0f + __expf(-qv));
                    out[idx] = sig * (own / (other + 1e-8f));
                }
            }
}

extern "C" void kernel_launch(void* const* d_in, const int* in_sizes, int n_in,
                              void* d_out, int out_size, void* d_ws, size_t ws_size,
                              hipStream_t stream) {
    const float* query = (const float*)d_in[0];
    const float* key_  = (const float*)d_in[1];
    const float* value = (const float*)d_in[2];
    const float* dist  = (const float*)d_in[3];
    const float* Wq = (const float*)d_in[4];
    const float* bq = (const float*)d_in[5];
    const float* Wk = (const float*)d_in[6];
    const float* bk = (const float*)d_in[7];
    const float* Wv = (const float*)d_in[8];
    const float* bv = (const float*)d_in[9];
    const float* alpha_raw = (const float*)d_in[10];
    float* out = (float*)d_out;

    // ws (512 MiB): Pt 32M | ea 64M | Xb 3x16.8M | qb 16.8M | Wb 384K
    unsigned short* Pt = (unsigned short*)d_ws;
    unsigned short* ea = Pt + (size_t)NBATCH * 512 * NG;
    unsigned short* Xb = ea + (size_t)NBATCH * NG * NG;
    const size_t XN = (size_t)NBATCH * NG * DM;
    unsigned short* qb = Xb + 3 * XN;
    unsigned short* Wb = qb + XN;

    wpack_kernel<<<dim3(192), dim3(256), 0, stream>>>(Wq, Wk, Wv, Wb);
    conv3_kernel<<<dim3(12288), dim3(256), 0, stream>>>(query, key_, value, Xb);

    projq_kernel<<<dim3(512), dim3(256), 0, stream>>>(Xb, Wb, bq, qb);
    projkv_kernel<<<dim3(512), dim3(256), 0, stream>>>(
        Xb + XN, Xb + 2 * XN, Wb + 65536, Wb + 131072, bk, bv, Pt);

    exp_kernel<<<dim3(16384), dim3(256), 0, stream>>>(dist, ea, alpha_raw);
    attn_kernel<<<dim3(1024), dim3(256), 0, stream>>>(ea, Pt, qb, out);
}

// Round 19
// 174.787 us; speedup vs baseline: 1.0726x; 1.0726x over previous
//
#include <hip/hip_runtime.h>
#include <hip/hip_bf16.h>

#define NBATCH 32
#define NG 1024
#define DM 256

typedef short bf16x8 __attribute__((ext_vector_type(8)));
typedef float f32x4 __attribute__((ext_vector_type(4)));
typedef unsigned short u16x4 __attribute__((ext_vector_type(4)));
typedef unsigned short u16x8 __attribute__((ext_vector_type(8)));

static __device__ __forceinline__ unsigned short f2bf(float f) {
    __hip_bfloat16 h = __float2bfloat16(f);
    return *reinterpret_cast<unsigned short*>(&h);
}
static __device__ __forceinline__ float bf2f(unsigned short u) {
    unsigned int x = ((unsigned int)u) << 16;
    return *reinterpret_cast<float*>(&x);
}

// async global->LDS, 16B per lane. LDS dest wave-uniform (HW adds lane*16);
// global source is per-lane.
static __device__ __forceinline__ void gload16(const void* g, void* l) {
    __builtin_amdgcn_global_load_lds(
        (const __attribute__((address_space(1))) unsigned int*)g,
        (__attribute__((address_space(3))) unsigned int*)l, 16, 0, 0);
}

// counted-vmcnt barrier pairs (T4)
static __device__ __forceinline__ void wait_vm8_bar() {
    asm volatile("s_waitcnt vmcnt(8)" ::: "memory");
    asm volatile("s_barrier" ::: "memory");
    __builtin_amdgcn_sched_barrier(0);
}
static __device__ __forceinline__ void wait_vm0_bar() {
    asm volatile("s_waitcnt vmcnt(0)" ::: "memory");
    asm volatile("s_barrier" ::: "memory");
    __builtin_amdgcn_sched_barrier(0);
}
static __device__ __forceinline__ void bar_only() {
    asm volatile("s_barrier" ::: "memory");
}

// ---------------------------------------------------------------------------
// Kernel P: merged prep — conv3 (blocks 0..12287) | exp (12288..28671) |
// wpack (28672..28863). One launch; measured ~53 us clean (r17 vs r18 delta).
// ---------------------------------------------------------------------------
__global__ __launch_bounds__(256) void prep_kernel(
    const float* __restrict__ q, const float* __restrict__ k,
    const float* __restrict__ v, const float* __restrict__ dist,
    const float* __restrict__ Wq, const float* __restrict__ Wk,
    const float* __restrict__ Wv, const float* __restrict__ alpha_raw,
    unsigned short* __restrict__ Xb, unsigned short* __restrict__ ea,
    unsigned short* __restrict__ Wb)
{
    const int bid = blockIdx.x;
    if (bid < 12288) {
        const int sel = bid >> 12;
        const float* src = (sel == 0) ? q : (sel == 1) ? k : v;
        const size_t i8 = (((size_t)(bid & 4095)) * 256 + threadIdx.x) * 8;
        float4 a = *(const float4*)(src + i8);
        float4 c = *(const float4*)(src + i8 + 4);
        *(u16x8*)(Xb + (size_t)sel * NBATCH * NG * DM + i8) =
            (u16x8){ f2bf(a.x), f2bf(a.y), f2bf(a.z), f2bf(a.w),
                     f2bf(c.x), f2bf(c.y), f2bf(c.z), f2bf(c.w) };
    } else if (bid < 28672) {
        const float alpha = log1pf(__expf(alpha_raw[0])) + 1e-6f;
        const float sc = -alpha * 10.0f * 1.44269504088896f;
        const size_t i8 = (((size_t)(bid - 12288)) * 256 + threadIdx.x) * 8;
        float4 v0 = *(const float4*)(dist + i8);
        float4 v1 = *(const float4*)(dist + i8 + 4);
        *(u16x8*)(ea + i8) =
            (u16x8){ f2bf(exp2f(sc * v0.x)), f2bf(exp2f(sc * v0.y)),
                     f2bf(exp2f(sc * v0.z)), f2bf(exp2f(sc * v0.w)),
                     f2bf(exp2f(sc * v1.x)), f2bf(exp2f(sc * v1.y)),
                     f2bf(exp2f(sc * v1.z)), f2bf(exp2f(sc * v1.w)) };
    } else {
        const int i4 = ((bid - 28672) * 256 + threadIdx.x) * 4;
        const int t = i4 >> 16;
        const int off = i4 & 65535;
        const float* src = (t == 0) ? Wq : (t == 1) ? Wk : Wv;
        float4 w4 = *(const float4*)(src + off);
        *(u16x4*)(Wb + i4) = (u16x4){ f2bf(w4.x), f2bf(w4.y), f2bf(w4.z), f2bf(w4.w) };
    }
}

// ---------------------------------------------------------------------------
// Kernel Q: qb = bf16(Xq @ Wq^T + bq)  (pre-sigmoid; attn applies sigmoid).
// dbuf + counted-vmcnt (T4), proven structure.
// ---------------------------------------------------------------------------
__global__ __launch_bounds__(256) void projq_kernel(
    const unsigned short* __restrict__ Xq,   // [32768][256] bf16
    const unsigned short* __restrict__ Wb,   // [256][256] bf16 (Wq)
    const float* __restrict__ bq,
    unsigned short* __restrict__ qb)         // [32768][256] bf16
{
    __shared__ __align__(128) unsigned short lds[2][2][128 * 64];

    const int bid = blockIdx.x;
    const int mt = bid >> 1, nt = bid & 1;
    const int tid = threadIdx.x;
    const int w = tid >> 6, lane = tid & 63;
    const int wm = w >> 1, wn = w & 1;
    const int l15 = lane & 15, lhi = lane >> 4;
    const int lr = lane >> 3, sl = lane & 7;
    const int sp = sl ^ lr;

    const char* Abase = (const char*)(Xq + (size_t)mt * 128 * 256);
    const char* Wbase = (const char*)(Wb + (size_t)nt * 128 * 256);

    f32x4 acc[4][4];
    #pragma unroll
    for (int mi = 0; mi < 4; ++mi)
        #pragma unroll
        for (int ni = 0; ni < 4; ++ni)
            acc[mi][ni] = (f32x4){0.f, 0.f, 0.f, 0.f};

    auto STAGE = [&](int buf, int t) {
        #pragma unroll
        for (int i = 0; i < 4; ++i) {
            const int r = w * 32 + i * 8 + lr;
            gload16(Abase + (size_t)r * 512 + t * 128 + sp * 16,
                    (char*)&lds[buf][0][0] + w * 4096 + i * 1024);
            gload16(Wbase + (size_t)r * 512 + t * 128 + sp * 16,
                    (char*)&lds[buf][1][0] + w * 4096 + i * 1024);
        }
    };

    STAGE(0, 0);
    int cur = 0;
    for (int t = 0; t < 4; ++t) {
        if (t < 3) { STAGE(cur ^ 1, t + 1); wait_vm8_bar(); }
        else       { wait_vm0_bar(); }
        const char* Ab = (const char*)&lds[cur][0][0];
        const char* Bb = (const char*)&lds[cur][1][0];
        #pragma unroll
        for (int kk = 0; kk < 2; ++kk) {
            bf16x8 af[4], bfr[4];
            #pragma unroll
            for (int mi = 0; mi < 4; ++mi) {
                const int tr = wm * 64 + mi * 16 + l15;
                af[mi] = *(const bf16x8*)(Ab + ((tr * 128 + kk * 64 + lhi * 16) ^ ((tr & 7) << 4)));
            }
            #pragma unroll
            for (int ni = 0; ni < 4; ++ni) {
                const int tr = wn * 64 + ni * 16 + l15;
                bfr[ni] = *(const bf16x8*)(Bb + ((tr * 128 + kk * 64 + lhi * 16) ^ ((tr & 7) << 4)));
            }
            #pragma unroll
            for (int mi = 0; mi < 4; ++mi)
                #pragma unroll
                for (int ni = 0; ni < 4; ++ni)
                    acc[mi][ni] = __builtin_amdgcn_mfma_f32_16x16x32_bf16(
                        af[mi], bfr[ni], acc[mi][ni], 0, 0, 0);
        }
        bar_only();
        cur ^= 1;
    }

    #pragma unroll
    for (int ni = 0; ni < 4; ++ni) {
        const int c = nt * 128 + wn * 64 + ni * 16 + l15;
        const float bqs = bq[c];
        #pragma unroll
        for (int mi = 0; mi < 4; ++mi)
            #pragma unroll
            for (int r = 0; r < 4; ++r) {
                const size_t R = (size_t)mt * 128 + wm * 64 + mi * 16 + lhi * 4 + r;
                qb[R * DM + c] = f2bf(acc[mi][ni][r] + bqs);
            }
    }
}

// ---------------------------------------------------------------------------
// Kernel KV: k, v projections fused (row = [k 64B | v 64B]); dbuf + T4.
// Pt rows 2c/2c+1 = exp(k)*v / exp(k).
// ---------------------------------------------------------------------------
__global__ __launch_bounds__(256) void projkv_kernel(
    const unsigned short* __restrict__ Xk,
    const unsigned short* __restrict__ Xv,
    const unsigned short* __restrict__ Wkb,
    const unsigned short* __restrict__ Wvb,
    const float* __restrict__ bk, const float* __restrict__ bv,
    unsigned short* __restrict__ Pt)
{
    __shared__ __align__(128) unsigned short lds[2][2][128 * 64];

    const int bid = blockIdx.x;
    const int mt = bid >> 1, nt = bid & 1;
    const int tid = threadIdx.x;
    const int w = tid >> 6, lane = tid & 63;
    const int wm = w >> 1, wn = w & 1;
    const int l15 = lane & 15, lhi = lane >> 4;
    const int lr = lane >> 3, sl = lane & 7;
    const int sp = sl ^ lr;
    const int g16 = (sp & 3) * 16;

    f32x4 kacc[4][4], vacc[4][4];
    #pragma unroll
    for (int mi = 0; mi < 4; ++mi)
        #pragma unroll
        for (int ni = 0; ni < 4; ++ni) {
            kacc[mi][ni] = (f32x4){0.f, 0.f, 0.f, 0.f};
            vacc[mi][ni] = (f32x4){0.f, 0.f, 0.f, 0.f};
        }

    auto STAGE = [&](int buf, int t) {
        #pragma unroll
        for (int i = 0; i < 4; ++i) {
            const int r = w * 32 + i * 8 + lr;
            const char* asrc = (sp < 4 ? (const char*)Xk : (const char*)Xv)
                               + (size_t)(mt * 128 + r) * 512 + t * 64 + g16;
            gload16(asrc, (char*)&lds[buf][0][0] + w * 4096 + i * 1024);
            const char* wsrc = (sp < 4 ? (const char*)Wkb : (const char*)Wvb)
                               + (size_t)(nt * 128 + r) * 512 + t * 64 + g16;
            gload16(wsrc, (char*)&lds[buf][1][0] + w * 4096 + i * 1024);
        }
    };

    STAGE(0, 0);
    int cur = 0;
    for (int t = 0; t < 8; ++t) {
        if (t < 7) { STAGE(cur ^ 1, t + 1); wait_vm8_bar(); }
        else       { wait_vm0_bar(); }
        const char* Ab = (const char*)&lds[cur][0][0];
        const char* Bb = (const char*)&lds[cur][1][0];
        bf16x8 kaf[4], vaf[4], kbf[4], vbf[4];
        #pragma unroll
        for (int mi = 0; mi < 4; ++mi) {
            const int tr = wm * 64 + mi * 16 + l15;
            const int sw = (tr & 7) << 4;
            kaf[mi] = *(const bf16x8*)(Ab + ((tr * 128 + lhi * 16) ^ sw));
            vaf[mi] = *(const bf16x8*)(Ab + ((tr * 128 + 64 + lhi * 16) ^ sw));
        }
        #pragma unroll
        for (int ni = 0; ni < 4; ++ni) {
            const int tr = wn * 64 + ni * 16 + l15;
            const int sw = (tr & 7) << 4;
            kbf[ni] = *(const bf16x8*)(Bb + ((tr * 128 + lhi * 16) ^ sw));
            vbf[ni] = *(const bf16x8*)(Bb + ((tr * 128 + 64 + lhi * 16) ^ sw));
        }
        #pragma unroll
        for (int mi = 0; mi < 4; ++mi)
            #pragma unroll
            for (int ni = 0; ni < 4; ++ni) {
                kacc[mi][ni] = __builtin_amdgcn_mfma_f32_16x16x32_bf16(
                    kaf[mi], kbf[ni], kacc[mi][ni], 0, 0, 0);
                vacc[mi][ni] = __builtin_amdgcn_mfma_f32_16x16x32_bf16(
                    vaf[mi], vbf[ni], vacc[mi][ni], 0, 0, 0);
            }
        bar_only();
        cur ^= 1;
    }

    const int b = (mt * 128) >> 10;
    const int kb0 = (mt * 128) & 1023;
    #pragma unroll
    for (int ni = 0; ni < 4; ++ni) {
        const int c = nt * 128 + wn * 64 + ni * 16 + l15;
        const float bks = bk[c], bvs = bv[c];
        #pragma unroll
        for (int mi = 0; mi < 4; ++mi) {
            unsigned short p1[4], p2[4];
            #pragma unroll
            for (int r = 0; r < 4; ++r) {
                const float ek = __expf(kacc[mi][ni][r] + bks);
                const float vv = vacc[mi][ni][r] + bvs;
                p1[r] = f2bf(ek * vv);
                p2[r] = f2bf(ek);
            }
            const int kidx = kb0 + wm * 64 + mi * 16 + lhi * 4;
            *(u16x4*)&Pt[((size_t)b * 512 + 2 * c    ) * NG + kidx] =
                (u16x4){p1[0], p1[1], p1[2], p1[3]};
            *(u16x4*)&Pt[((size_t)b * 512 + 2 * c + 1) * NG + kidx] =
                (u16x4){p2[0], p2[1], p2[2], p2[3]};
        }
    }
}

// ---------------------------------------------------------------------------
// Kernel C: out = sigmoid(q) * (num/den). r13 structure (best measured: 81us):
// 256x256 tile, BK=64, 512 threads (8 waves 2x4), dbuf 128 KB LDS, counted
// vmcnt(8); proven 128B-row XOR swizzle (0 conflicts). qb-fused sigmoid
// epilogue (saves sigq f32 round-trip). grid 256 = 32b x 4m x 2n, XCD-chunked.
// ---------------------------------------------------------------------------
__global__ __launch_bounds__(512, 2) void attn_kernel(
    const unsigned short* __restrict__ ea,
    const unsigned short* __restrict__ Pt,
    const unsigned short* __restrict__ qb,
    float* __restrict__ out)
{
    __shared__ __align__(128) char lds[2][2][32768];   // [buf][A/B][256 rows x 128B]

    const int bid = blockIdx.x;
    const int l = (bid & 7) * 32 + (bid >> 3);   // XCD-chunked, bijective
    const int b = l >> 3;          // 0..31
    const int m = (l >> 1) & 3;    // 0..3
    const int n = l & 1;           // 0..1

    const int tid = threadIdx.x;
    const int w = tid >> 6, lane = tid & 63;
    const int wm = w >> 2, wn = w & 3;           // wave grid 2x4
    const int l15 = lane & 15, lhi = lane >> 4;

    // staging: waves 0-3 stage A (rows 0-255), waves 4-7 stage B; 8 instr/wave
    const int isB = w >> 2;
    const int sw = w & 3;
    const int lr = lane >> 3;                    // row within 8-row group
    const int cbs = (lane & 7) ^ lr;             // inverse-swizzled src granule

    const char* Abase = (const char*)(ea + ((size_t)b * NG + m * 256) * NG);
    const char* Bbase = (const char*)(Pt + ((size_t)b * 512 + n * 256) * NG);
    const char* Sbase = isB ? Bbase : Abase;

    f32x4 acc[8][4];
    #pragma unroll
    for (int mi = 0; mi < 8; ++mi)
        #pragma unroll
        for (int ni = 0; ni < 4; ++ni)
            acc[mi][ni] = (f32x4){0.f, 0.f, 0.f, 0.f};

    // stage K-tile t (64 bf16 = 128B per row, 256 rows) into buf
    auto STAGE = [&](int buf, int t) {
        #pragma unroll
        for (int i = 0; i < 8; ++i) {
            const int r = sw * 64 + i * 8 + lr;          // 0..255; r&7 == lr
            gload16(Sbase + (size_t)r * 2048 + t * 128 + cbs * 16,
                    &lds[buf][isB][0] + sw * 8192 + i * 1024);
        }
    };

    STAGE(0, 0);
    int cur = 0;
    for (int t = 0; t < 16; ++t) {
        if (t < 15) { STAGE(cur ^ 1, t + 1); wait_vm8_bar(); }
        else        { wait_vm0_bar(); }
        const char* Ab = &lds[cur][0][0];
        const char* Bb = &lds[cur][1][0];
        #pragma unroll
        for (int kk = 0; kk < 2; ++kk) {
            bf16x8 af[8], bfr[4];
            #pragma unroll
            for (int mi = 0; mi < 8; ++mi) {
                const int tr = wm * 128 + mi * 16 + l15;
                af[mi] = *(const bf16x8*)(Ab + ((tr * 128 + kk * 64 + lhi * 16) ^ ((tr & 7) << 4)));
            }
            #pragma unroll
            for (int ni = 0; ni < 4; ++ni) {
                const int tr = wn * 64 + ni * 16 + l15;
                bfr[ni] = *(const bf16x8*)(Bb + ((tr * 128 + kk * 64 + lhi * 16) ^ ((tr & 7) << 4)));
            }
            #pragma unroll
            for (int mi = 0; mi < 8; ++mi)
                #pragma unroll
                for (int ni = 0; ni < 4; ++ni)
                    acc[mi][ni] = __builtin_amdgcn_mfma_f32_16x16x32_bf16(
                        af[mi], bfr[ni], acc[mi][ni], 0, 0, 0);
        }
        bar_only();
        cur ^= 1;
    }

    // epilogue: even col = numerator, odd = denominator (same d); sigmoid(q)
    const int parity = lane & 1;
    #pragma unroll
    for (int mi = 0; mi < 8; ++mi)
        #pragma unroll
        for (int ni = 0; ni < 4; ++ni)
            #pragma unroll
            for (int r = 0; r < 4; ++r) {
                const float own = acc[mi][ni][r];
                const float other = __shfl_xor(own, 1, 64);
                if (!parity) {
                    const int colg = n * 256 + wn * 64 + ni * 16 + l15;   // even
                    const int d = colg >> 1;
                    const int rowg = m * 256 + wm * 128 + mi * 16 + lhi * 4 + r;
                    const size_t idx = ((size_t)b * NG + rowg) * DM + d;
                    const float qv = bf2f(qb[idx]);
                    const float sig = 1.0f / (1.0f + __expf(-qv));
                    out[idx] = sig * (own / (other + 1e-8f));
                }
            }
}

extern "C" void kernel_launch(void* const* d_in, const int* in_sizes, int n_in,
                              void* d_out, int out_size, void* d_ws, size_t ws_size,
                              hipStream_t stream) {
    const float* query = (const float*)d_in[0];
    const float* key_  = (const float*)d_in[1];
    const float* value = (const float*)d_in[2];
    const float* dist  = (const float*)d_in[3];
    const float* Wq = (const float*)d_in[4];
    const float* bq = (const float*)d_in[5];
    const float* Wk = (const float*)d_in[6];
    const float* bk = (const float*)d_in[7];
    const float* Wv = (const float*)d_in[8];
    const float* bv = (const float*)d_in[9];
    const float* alpha_raw = (const float*)d_in[10];
    float* out = (float*)d_out;

    // ws (512 MiB): Pt 32M | ea 64M | Xb 3x16.8M | qb 16.8M | Wb 384K
    unsigned short* Pt = (unsigned short*)d_ws;
    unsigned short* ea = Pt + (size_t)NBATCH * 512 * NG;
    unsigned short* Xb = ea + (size_t)NBATCH * NG * NG;
    const size_t XN = (size_t)NBATCH * NG * DM;
    unsigned short* qb = Xb + 3 * XN;
    unsigned short* Wb = qb + XN;

    prep_kernel<<<dim3(28864), dim3(256), 0, stream>>>(
        query, key_, value, dist, Wq, Wk, Wv, alpha_raw, Xb, ea, Wb);

    projq_kernel<<<dim3(512), dim3(256), 0, stream>>>(Xb, Wb, bq, qb);
    projkv_kernel<<<dim3(512), dim3(256), 0, stream>>>(
        Xb + XN, Xb + 2 * XN, Wb + 65536, Wb + 131072, bk, bv, Pt);

    attn_kernel<<<dim3(256), dim3(512), 0, stream>>>(ea, Pt, qb, out);
}